// Round 1
// baseline (14424.216 us; speedup 1.0000x reference)
//
#include <hip/hip_runtime.h>
#include <math.h>

// EBT_GRC beam-search forward, fp32 baseline (round 1).
// N=256, S=32, D=512, CH=2048, BEAM=5. Needs ~204 MiB of d_ws.
//
// Key algorithmic choice: pair-score cache. Reference recomputes all
// w[n,b,s] each iteration; only pairs touching the merged position change.
// Cached values were produced by the SAME kernel math on bitwise-identical
// content vectors, so cache+gather == full recompute exactly.

#define NN   256
#define S0   32
#define WDIM 512
#define DD   512
#define CHID 2048
#define BEAM 5
#define NB   (NN*BEAM)   // 1280

__device__ __forceinline__ float gelu_f(float x) {
    return 0.5f * x * (1.0f + erff(x * 0.7071067811865475f));
}

__device__ __forceinline__ float block_reduce_sum(float v, float* sb) {
    #pragma unroll
    for (int o = 32; o > 0; o >>= 1) v += __shfl_down(v, o);
    const int lane = threadIdx.x & 63, wid = threadIdx.x >> 6;
    __syncthreads();
    if (lane == 0) sb[wid] = v;
    __syncthreads();
    return sb[0] + sb[1] + sb[2] + sb[3];   // deterministic order
}

// ---------------- generic fp32 GEMM: C = act(A@B + bias) ----------------
// A: M x K row-major, B: K x Nn row-major, C: M x Nn. M%64==0, Nn%64==0, K%16==0.
__global__ __launch_bounds__(256) void k_gemm(
    const float* __restrict__ A, const float* __restrict__ B,
    const float* __restrict__ bias, float* __restrict__ C,
    int M, int Nn, int K, int act)
{
    __shared__ float As[16][68];   // [k][m], +4 pad keeps 16B align + no write conflicts
    __shared__ float Bs[16][64];   // [k][n]
    const int t  = threadIdx.x;
    const int tm = t >> 4, tn = t & 15;
    const int bn = blockIdx.x * 64, bm = blockIdx.y * 64;
    const int lm = t & 63, lkq = t >> 6;
    float acc[4][4] = {{0.f,0.f,0.f,0.f},{0.f,0.f,0.f,0.f},
                       {0.f,0.f,0.f,0.f},{0.f,0.f,0.f,0.f}};
    for (int k0 = 0; k0 < K; k0 += 16) {
        __syncthreads();
        float4 av = *(const float4*)(A + (size_t)(bm + lm) * K + (k0 + 4*lkq));
        As[4*lkq+0][lm] = av.x; As[4*lkq+1][lm] = av.y;
        As[4*lkq+2][lm] = av.z; As[4*lkq+3][lm] = av.w;
        *(float4*)&Bs[tm][4*tn] =
            *(const float4*)(B + (size_t)(k0 + tm) * Nn + (bn + 4*tn));
        __syncthreads();
        #pragma unroll
        for (int kk = 0; kk < 16; ++kk) {
            float4 a4 = *(const float4*)&As[kk][4*tm];
            float4 b4 = *(const float4*)&Bs[kk][4*tn];
            float ar[4] = {a4.x, a4.y, a4.z, a4.w};
            float br[4] = {b4.x, b4.y, b4.z, b4.w};
            #pragma unroll
            for (int x = 0; x < 4; ++x)
                #pragma unroll
                for (int y = 0; y < 4; ++y)
                    acc[x][y] = fmaf(ar[x], br[y], acc[x][y]);
        }
    }
    #pragma unroll
    for (int x = 0; x < 4; ++x) {
        const int m = bm + 4*tm + x;
        #pragma unroll
        for (int y = 0; y < 4; ++y) {
            const int n = bn + 4*tn + y;
            float v = acc[x][y] + bias[n];
            if (act) v = gelu_f(v);
            C[(size_t)m * Nn + n] = v;
        }
    }
}

// ---------------- init layernorm: content[n,0,s,:] = LN(y[row]) ----------------
__global__ __launch_bounds__(256) void k_ln_init(
    const float* __restrict__ y, const float* __restrict__ g,
    const float* __restrict__ b, float* __restrict__ content)
{
    const int row = blockIdx.x;            // n*32 + s
    const int n = row >> 5, s = row & 31;
    const float* yr = y + (size_t)row * DD;
    const int t = threadIdx.x;
    float v0 = yr[t], v1 = yr[t + 256];
    __shared__ float sb[8];
    float s1 = block_reduce_sum(v0 + v1, sb);
    float s2 = block_reduce_sum(v0*v0 + v1*v1, sb);
    float mu = s1 * (1.f/512.f);
    float rstd = rsqrtf(s2 * (1.f/512.f) - mu*mu + 1e-5f);
    float* o = content + (((size_t)n*BEAM + 0)*S0 + s) * DD;
    o[t]       = (v0 - mu) * rstd * g[t]       + b[t];
    o[t + 256] = (v1 - mu) * rstd * g[t + 256] + b[t + 256];
}

__global__ void k_init_state(float* accu, float* bm) {
    int i = blockIdx.x * blockDim.x + threadIdx.x;
    if (i < NB) { accu[i] = 0.f; bm[i] = 1.f; }
}

// ---------------- pair scores ----------------
// mode 0 (full, i=0): row r -> n=r/S, b=0, s=r%S.
// mode 1 (incremental): row r -> nk=r>>1, slot=r&1, jw=pos[nk]-1+slot; valid if 0<=jw<S.
// Per-row math is identical & placement-independent in both modes (cache coherence).
__global__ __launch_bounds__(256) void k_score(
    const float* __restrict__ content, const float* __restrict__ Wd1,
    const float* __restrict__ bd1, const float* __restrict__ Wd2,
    const float* __restrict__ bd2, float* __restrict__ w,
    const int* __restrict__ posb, int mode, int S, int nrows)
{
    __shared__ float cat[8][1024];         // 32 KB; reused as reduce buffer
    const int t = threadIdx.x;
    const float* src[8];
    int wix[8]; bool valid[8];
    #pragma unroll
    for (int j = 0; j < 8; ++j) {
        int r = blockIdx.x * 8 + j;
        if (r >= nrows) r = nrows - 1;
        if (mode == 0) {
            int n = r / S, s = r - n * S;
            src[j]   = content + (((size_t)n*BEAM + 0)*S0 + s) * DD;
            wix[j]   = (n*BEAM + 0)*S0 + s;
            valid[j] = true;
        } else {
            int nk = r >> 1, slot = r & 1;
            int s = posb[nk];
            int jw = s - 1 + slot;
            valid[j] = (jw >= 0 && jw < S);
            int jc = jw < 0 ? 0 : (jw > S-1 ? S-1 : jw);
            src[j] = content + ((size_t)nk * S0 + jc) * DD;
            wix[j] = nk * S0 + jc;
        }
    }
    #pragma unroll
    for (int j = 0; j < 8; ++j)
        *(float4*)&cat[j][4*t] = *(const float4*)(src[j] + 4*t);
    __syncthreads();

    const int c0 = 2*t, c1 = 2*t + 1;
    float a0[8] = {0,0,0,0,0,0,0,0}, a1[8] = {0,0,0,0,0,0,0,0};
    for (int k4 = 0; k4 < 1024; k4 += 4) {
        float2 w0 = *(const float2*)(Wd1 + (size_t)(k4+0)*DD + c0);
        float2 w1 = *(const float2*)(Wd1 + (size_t)(k4+1)*DD + c0);
        float2 w2 = *(const float2*)(Wd1 + (size_t)(k4+2)*DD + c0);
        float2 w3 = *(const float2*)(Wd1 + (size_t)(k4+3)*DD + c0);
        #pragma unroll
        for (int j = 0; j < 8; ++j) {
            float4 a = *(const float4*)&cat[j][k4];
            a0[j] = fmaf(a.x, w0.x, a0[j]); a1[j] = fmaf(a.x, w0.y, a1[j]);
            a0[j] = fmaf(a.y, w1.x, a0[j]); a1[j] = fmaf(a.y, w1.y, a1[j]);
            a0[j] = fmaf(a.z, w2.x, a0[j]); a1[j] = fmaf(a.z, w2.y, a1[j]);
            a0[j] = fmaf(a.w, w3.x, a0[j]); a1[j] = fmaf(a.w, w3.y, a1[j]);
        }
    }
    const float b0 = bd1[c0], b1 = bd1[c1];
    const float u0 = Wd2[c0], u1 = Wd2[c1];
    const float bd2v = bd2[0];
    __syncthreads();
    float* red = &cat[0][0];
    #pragma unroll
    for (int j = 0; j < 8; ++j) {
        float h0 = gelu_f(a0[j] + b0);
        float h1 = gelu_f(a1[j] + b1);
        red[j*256 + t] = h0*u0 + h1*u1;
    }
    __syncthreads();
    for (int off = 128; off > 0; off >>= 1) {
        if (t < off) {
            #pragma unroll
            for (int j = 0; j < 8; ++j) red[j*256 + t] += red[j*256 + t + off];
        }
        __syncthreads();
    }
    #pragma unroll
    for (int j = 0; j < 8; ++j)
        if (t == j && valid[j] && blockIdx.x*8 + j < nrows)
            w[wix[j]] = red[j*256] + bd2v;
}

// ---------------- top-k positions + beam selection ----------------
__global__ __launch_bounds__(64) void k_topk(
    const float* __restrict__ w, const float* __restrict__ accu,
    const float* __restrict__ bmask, const float* __restrict__ maskg,
    int iiter, int B, int S, int topk, int do_bsel,
    int* __restrict__ parent, int* __restrict__ posb,
    float* __restrict__ accu_out, float* __restrict__ bm_out)
{
    const int n = blockIdx.x, lane = threadIdx.x;
    __shared__ int   selpos_s[BEAM][BEAM];
    __shared__ float nscore_s[BEAM][BEAM];
    const float* mrow = maskg + n*S0 + (iiter + 1);
    const float mk   = (lane < S) ? mrow[lane] : 0.f;
    const float done = 1.f - mrow[0];
    for (int b = 0; b < B; ++b) {
        float ml;
        if (lane < S) {
            float wv = w[(n*BEAM + b)*S0 + lane];
            ml = (mk > 0.f) ? wv : -1e9f;
        } else ml = -INFINITY;
        float mx = ml;
        #pragma unroll
        for (int o = 32; o > 0; o >>= 1) mx = fmaxf(mx, __shfl_xor(mx, o));
        float e = (lane < S) ? expf(ml - mx) * mk : 0.f;
        float es = e;
        #pragma unroll
        for (int o = 32; o > 0; o >>= 1) es += __shfl_xor(es, o);
        const float den = es + 1e-20f;
        float mlc = ml;
        for (int ts = 0; ts < topk; ++ts) {
            // key: value desc, index asc (matches jax.lax.top_k)
            unsigned int fb = __float_as_uint(mlc);
            unsigned int ok = (fb & 0x80000000u) ? ~fb : (fb | 0x80000000u);
            unsigned long long key =
                ((unsigned long long)ok << 32) | (unsigned int)(63 - lane);
            if (lane >= S) key = 0ull;
            unsigned long long km = key;
            #pragma unroll
            for (int o = 32; o > 0; o >>= 1) {
                unsigned long long oth = __shfl_xor(km, o);
                km = (oth > km) ? oth : km;
            }
            int sidx = 63 - (int)(km & 0xffffffffull);
            float esel = __shfl(e, sidx);
            if (lane == 0) {
                selpos_s[b][ts] = sidx;
                nscore_s[b][ts] = logf(esel / den + 1e-20f);
            }
            if (lane == sidx) mlc = -INFINITY;
        }
    }
    __syncthreads();
    if (lane == 0) {
        float acand[BEAM*BEAM], bcand[BEAM*BEAM];
        const int C = B * topk;
        for (int b = 0; b < B; ++b)
            for (int tt = 0; tt < topk; ++tt) {
                int c = b*topk + tt;
                acand[c] = accu[n*BEAM + b] + nscore_s[b][tt];
                float nb = done * ((tt == 0) ? 1.f : 0.f) + (1.f - done);
                bcand[c] = bmask[n*BEAM + b] * nb;
            }
        bool used[BEAM*BEAM];
        for (int c = 0; c < C; ++c) used[c] = false;
        for (int k = 0; k < BEAM; ++k) {
            int bestc;
            if (do_bsel) {
                bestc = 0; float bv = -INFINITY;
                for (int c = 0; c < C; ++c) {
                    if (used[c]) continue;
                    float v = (bcand[c] > 0.f) ? acand[c] : -1e9f;
                    if (v > bv) { bv = v; bestc = c; }
                }
                used[bestc] = true;
            } else bestc = k;
            parent[n*BEAM + k]   = bestc / topk;
            posb[n*BEAM + k]     = selpos_s[bestc / topk][bestc % topk];
            accu_out[n*BEAM + k] = acand[bestc];
            bm_out[n*BEAM + k]   = bcand[bestc];
        }
    }
}

// ---------------- gather [l,r] rows for grc (contiguous in content) ----------------
__global__ __launch_bounds__(256) void k_lrgather(
    const float* __restrict__ content, const int* __restrict__ parent,
    const int* __restrict__ posb, int finalflag, float* __restrict__ lr)
{
    const int row = blockIdx.x;            // n*BEAM + k
    int p, s;
    if (finalflag) { p = row % BEAM; s = 0; }
    else           { p = parent[row]; s = posb[row]; }
    const int n = row / BEAM;
    const float4* src = (const float4*)(content + (((size_t)n*BEAM + p)*S0 + s) * DD);
    float4* dst = (float4*)(lr + (size_t)row * 1024);
    dst[threadIdx.x] = src[threadIdx.x];   // 256 x float4 = 1024 floats
}

// ---------------- gate softmax + mix + layernorm ----------------
__global__ __launch_bounds__(256) void k_combine(
    const float* __restrict__ cc, const float* __restrict__ lr,
    const float* __restrict__ gp, const float* __restrict__ bp,
    float* __restrict__ nv)
{
    const int row = blockIdx.x, t = threadIdx.x;
    const float* c = cc + (size_t)row * CHID;
    const float* l = lr + (size_t)row * 1024;
    const float* r = l + DD;
    float o[2];
    #pragma unroll
    for (int e = 0; e < 2; ++e) {
        int d = t + 256*e;
        float c0 = c[d], c1 = c[DD + d], c2 = c[2*DD + d], c3 = c[3*DD + d];
        float m = fmaxf(c0, fmaxf(c1, c2));
        float e0 = expf(c0 - m), e1 = expf(c1 - m), e2 = expf(c2 - m);
        float inv = 1.f / (e0 + e1 + e2);
        o[e] = (e0*l[d] + e1*r[d] + e2*c3) * inv;
    }
    __shared__ float sb[8];
    float s1 = block_reduce_sum(o[0] + o[1], sb);
    float s2 = block_reduce_sum(o[0]*o[0] + o[1]*o[1], sb);
    float mu = s1 * (1.f/512.f);
    float rstd = rsqrtf(s2 * (1.f/512.f) - mu*mu + 1e-5f);
    #pragma unroll
    for (int e = 0; e < 2; ++e) {
        int d = t + 256*e;
        nv[(size_t)row*DD + d] = (o[e] - mu) * rstd * gp[d] + bp[d];
    }
}

// ---------------- content rebuild (merge at pos, beam gather, done-blend) --------
__global__ __launch_bounds__(256) void k_rebuild(
    const float* __restrict__ oldc, const float* __restrict__ nv,
    const int* __restrict__ parent, const int* __restrict__ posb,
    const float* __restrict__ maskg, int iiter, int Spnew,
    float* __restrict__ newc)
{
    const int nk = blockIdx.x;
    const int n = nk / BEAM;
    const int p = parent[nk], s = posb[nk];
    const float done = maskg[n*S0 + iiter + 1];
    const float4* ob = (const float4*)(oldc + (((size_t)n*BEAM + p) * S0) * DD);
    const float4* nb = (const float4*)(nv + (size_t)nk * DD);
    float4* dst = (float4*)(newc + ((size_t)nk * S0) * DD);
    const int total = Spnew * 128;         // float4 count (128 per position)
    for (int idx = threadIdx.x; idx < total; idx += 256) {
        int j = idx >> 7, d = idx & 127;
        float4 v = (j < s) ? ob[j*128 + d] : (j == s ? nb[d] : ob[(j+1)*128 + d]);
        if (done != 1.0f) {
            float4 tr = ob[j*128 + d];
            v.x = done*v.x + (1.f-done)*tr.x;  v.y = done*v.y + (1.f-done)*tr.y;
            v.z = done*v.z + (1.f-done)*tr.z;  v.w = done*v.w + (1.f-done)*tr.w;
        }
        dst[j*128 + d] = v;
    }
}

// ---------------- score cache gather (recompute slots filled by k_score mode 1) --
__global__ __launch_bounds__(64) void k_wgather(
    const float* __restrict__ wold, const int* __restrict__ parent,
    const int* __restrict__ posb, int Snew, float* __restrict__ wnew)
{
    const int n = blockIdx.x, lane = threadIdx.x;
    for (int k = 0; k < BEAM; ++k) {
        const int p = parent[n*BEAM + k], s = posb[n*BEAM + k];
        if (lane < Snew) {
            float v = 0.f;
            if (lane < s - 1)      v = wold[(n*BEAM + p)*S0 + lane];
            else if (lane > s)     v = wold[(n*BEAM + p)*S0 + lane + 1];
            wnew[(n*BEAM + k)*S0 + lane] = v;   // s-1, s overwritten by k_score(incr)
        }
    }
}

// ---------------- final beam softmax mix ----------------
__global__ __launch_bounds__(256) void k_final(
    const float* __restrict__ nv, const float* __restrict__ accu,
    const float* __restrict__ bmv, float* __restrict__ out)
{
    const int n = blockIdx.x, t = threadIdx.x;
    float sc[BEAM];
    #pragma unroll
    for (int k = 0; k < BEAM; ++k) {
        float m = bmv[n*BEAM + k];
        sc[k] = m * accu[n*BEAM + k] + (1.f - m) * (-999999.f);
    }
    float mx = sc[0];
    #pragma unroll
    for (int k = 1; k < BEAM; ++k) mx = fmaxf(mx, sc[k]);
    float e[BEAM], den = 0.f;
    #pragma unroll
    for (int k = 0; k < BEAM; ++k) { e[k] = expf(sc[k] - mx); den += e[k]; }
    const float inv = 1.f / den;
    #pragma unroll
    for (int i2 = 0; i2 < 2; ++i2) {
        int d = t + 256*i2;
        float s = 0.f;
        #pragma unroll
        for (int k = 0; k < BEAM; ++k)
            s += e[k]*inv * nv[((size_t)n*BEAM + k)*DD + d];
        out[(size_t)n*DD + d] = s;
    }
}

extern "C" void kernel_launch(void* const* d_in, const int* in_sizes, int n_in,
                              void* d_out, int out_size, void* d_ws, size_t ws_size,
                              hipStream_t stream) {
    (void)in_sizes; (void)n_in; (void)out_size; (void)ws_size;
    const float* x    = (const float*)d_in[0];
    const float* mask = (const float*)d_in[1];
    const float* Wi   = (const float*)d_in[2];
    const float* bi   = (const float*)d_in[3];
    const float* g1   = (const float*)d_in[4];
    const float* b1   = (const float*)d_in[5];
    const float* Wd1  = (const float*)d_in[6];
    const float* bd1  = (const float*)d_in[7];
    const float* Wd2  = (const float*)d_in[8];
    const float* bd2  = (const float*)d_in[9];
    const float* Wc1  = (const float*)d_in[10];
    const float* bc1  = (const float*)d_in[11];
    const float* Wc2  = (const float*)d_in[12];
    const float* bc2  = (const float*)d_in[13];
    const float* g2   = (const float*)d_in[14];
    const float* b2   = (const float*)d_in[15];
    float* out = (float*)d_out;

    // workspace carve-up (floats); total ~204 MiB
    float* ws = (float*)d_ws;
    const size_t CN = (size_t)NN*BEAM*S0*DD;          // 20,971,520
    float* cA   = ws;
    float* cB   = cA + CN;
    float* ybuf = cB + CN;                             // NN*S0*DD
    float* lr   = ybuf + (size_t)NN*S0*DD;             // NB*1024
    float* hb   = lr + (size_t)NB*1024;                // NB*CHID
    float* cb   = hb + (size_t)NB*CHID;                // NB*CHID
    float* nvb  = cb + (size_t)NB*CHID;                // NB*DD
    float* wA   = nvb + (size_t)NB*DD;                 // NB*32
    float* wB   = wA + (size_t)NB*S0;
    float* accA = wB + (size_t)NB*S0;
    float* accB = accA + NB;
    float* bmA  = accB + NB;
    float* bmB  = bmA + NB;
    int* parent = (int*)(bmB + NB);
    int* posb   = parent + NB;

    // init: content[:,0] = LN(x@Wi+bi); accu=0, bm=1
    k_gemm<<<dim3(DD/64, (NN*S0)/64), 256, 0, stream>>>(x, Wi, bi, ybuf, NN*S0, DD, WDIM, 0);
    k_ln_init<<<NN*S0, 256, 0, stream>>>(ybuf, g1, b1, cA);
    k_init_state<<<(NB + 255)/256, 256, 0, stream>>>(accA, bmA);
    // full scores at i=0 (B=1, S=31)
    k_score<<<(NN*31)/8, 256, 0, stream>>>(cA, Wd1, bd1, Wd2, bd2, wA, nullptr, 0, 31, NN*31);

    float *ccur = cA, *cnxt = cB, *wcur = wA, *wnxt = wB;
    float *acur = accA, *anxt = accB, *bcur = bmA, *bnxt = bmB;
    for (int i = 0; i < 30; ++i) {
        const int B  = (i == 0) ? 1 : BEAM;
        const int Sp = S0 - i;            // content positions
        const int S  = Sp - 1;            // pair count
        const int tk = (S < BEAM) ? S : BEAM;
        const int dob = (B*tk > BEAM) ? 1 : 0;
        k_topk<<<NN, 64, 0, stream>>>(wcur, acur, bcur, mask, i, B, S, tk, dob,
                                      parent, posb, anxt, bnxt);
        k_lrgather<<<NB, 256, 0, stream>>>(ccur, parent, posb, 0, lr);
        k_gemm<<<dim3(CHID/64, NB/64), 256, 0, stream>>>(lr, Wc1, bc1, hb, NB, CHID, 2*DD, 1);
        k_gemm<<<dim3(CHID/64, NB/64), 256, 0, stream>>>(hb, Wc2, bc2, cb, NB, CHID, CHID, 0);
        k_combine<<<NB, 256, 0, stream>>>(cb, lr, g2, b2, nvb);
        k_rebuild<<<NB, 256, 0, stream>>>(ccur, nvb, parent, posb, mask, i, Sp - 1, cnxt);
        if (i < 29) {
            k_wgather<<<NN, 64, 0, stream>>>(wcur, parent, posb, S - 1, wnxt);
            k_score<<<(NB*2)/8, 256, 0, stream>>>(cnxt, Wd1, bd1, Wd2, bd2, wnxt,
                                                  posb, 1, S - 1, NB*2);
        }
        float* tp;
        tp = ccur; ccur = cnxt; cnxt = tp;
        tp = wcur; wcur = wnxt; wnxt = tp;
        tp = acur; acur = anxt; anxt = tp;
        tp = bcur; bcur = bnxt; bnxt = tp;
    }
    // final compose (i = 30): l = content[:,:,0], r = content[:,:,1]
    k_lrgather<<<NB, 256, 0, stream>>>(ccur, parent, posb, 1, lr);
    k_gemm<<<dim3(CHID/64, NB/64), 256, 0, stream>>>(lr, Wc1, bc1, hb, NB, CHID, 2*DD, 1);
    k_gemm<<<dim3(CHID/64, NB/64), 256, 0, stream>>>(hb, Wc2, bc2, cb, NB, CHID, CHID, 0);
    k_combine<<<NB, 256, 0, stream>>>(cb, lr, g2, b2, nvb);
    k_final<<<NN, 256, 0, stream>>>(nvb, acur, bcur, out);
}

// Round 4
// 10496.694 us; speedup vs baseline: 1.3742x; 1.3742x over previous
//
#include <hip/hip_runtime.h>
#include <math.h>

// EBT_GRC beam-search forward, round 4: GRC/init GEMMs on fp16x2 scaled-split
// MFMA (error ~2^-22, fp32-class => beam selections match reference).
// N=256, S=32, D=512, CH=2048, BEAM=5. Workspace ~214 MB.

#define NN   256
#define S0   32
#define WDIM 512
#define DD   512
#define CHID 2048
#define BEAM 5
#define NB   (NN*BEAM)   // 1280
#define RSCALE 2048.0f   // residual scale 2^11
#define RINV  (1.0f/2048.0f)

typedef __attribute__((ext_vector_type(8))) _Float16 f16x8;
typedef __attribute__((ext_vector_type(4))) _Float16 f16x4v;
typedef __attribute__((ext_vector_type(4))) float f32x4;

__device__ __forceinline__ float gelu_f(float x) {
    return 0.5f * x * (1.0f + erff(x * 0.7071067811865475f));
}

// fp16 scaled split: v = h + RINV * l  (l = fp16((v-h)*2^11), keeps residual normal)
__device__ __forceinline__ _Float16 hi16(float v) { return (_Float16)v; }
__device__ __forceinline__ _Float16 lo16(float v, _Float16 h) {
    return (_Float16)((v - (float)h) * RSCALE);
}

__device__ __forceinline__ void gload_lds16(const void* g, void* l) {
    __builtin_amdgcn_global_load_lds(
        (const __attribute__((address_space(1))) unsigned*)g,
        (__attribute__((address_space(3))) unsigned*)l, 16, 0, 0);
}

__device__ __forceinline__ float block_reduce_sum(float v, float* sb) {
    #pragma unroll
    for (int o = 32; o > 0; o >>= 1) v += __shfl_down(v, o);
    const int lane = threadIdx.x & 63, wid = threadIdx.x >> 6;
    __syncthreads();
    if (lane == 0) sb[wid] = v;
    __syncthreads();
    return sb[0] + sb[1] + sb[2] + sb[3];
}

// ================= fp16x2 scaled-split MFMA GEMM =================
// A = Ah + RINV*Al : M x K fp16 row-major. B^T = Bh + RINV*Bl : N x K fp16.
// C = A@B + bias. OUTMODE 0: fp32 store. OUTMODE 1: gelu -> fp16 h/l store.
// M%128==0, N%128==0, K%32==0. 128x128 tile, BK=32, global_load_lds width 16,
// 4 waves x (4x4 tiles of 16x16x32). acc0 = AhBh; acc1 = AhBl + AlBh.
template<int OUTMODE>
__global__ __launch_bounds__(256, 1) void k_mfma_gemm(
    const _Float16* __restrict__ Ah, const _Float16* __restrict__ Al,
    const _Float16* __restrict__ Bh, const _Float16* __restrict__ Bl,
    const float* __restrict__ bias, float* __restrict__ Cf,
    _Float16* __restrict__ Oh, _Float16* __restrict__ Ol,
    int M, int N, int K)
{
    __shared__ __align__(16) _Float16 lds[4 * 4096]; // Ah,Al,Bh,Bl tiles [128][32]
    const int t = threadIdx.x, wave = t >> 6, lane = t & 63;
    const int bm = blockIdx.y * 128, bn = blockIdx.x * 128;
    const int wm = (wave >> 1) * 64, wn = (wave & 1) * 64;
    const int rsub = lane >> 2, seg = lane & 3;      // staging: 16 rows / 1 KB inst
    const int fm = lane & 15, fko = (lane >> 4) * 8; // fragment addressing

    f32x4 acc0[4][4], acc1[4][4];
    #pragma unroll
    for (int i = 0; i < 4; ++i)
        #pragma unroll
        for (int j = 0; j < 4; ++j) {
            acc0[i][j] = (f32x4){0.f, 0.f, 0.f, 0.f};
            acc1[i][j] = (f32x4){0.f, 0.f, 0.f, 0.f};
        }

    for (int k0 = 0; k0 < K; k0 += 32) {
        __syncthreads();
        #pragma unroll
        for (int j = 0; j < 2; ++j) {
            const int q = wave * 2 + j;              // 0..7: 16-row slab
            const size_t aoff = (size_t)(bm + q*16 + rsub) * K + k0 + seg * 8;
            const size_t boff = (size_t)(bn + q*16 + rsub) * K + k0 + seg * 8;
            gload_lds16(Ah + aoff, &lds[0*4096 + q*512]);
            gload_lds16(Al + aoff, &lds[1*4096 + q*512]);
            gload_lds16(Bh + boff, &lds[2*4096 + q*512]);
            gload_lds16(Bl + boff, &lds[3*4096 + q*512]);
        }
        __syncthreads();
        f16x8 ah[4], al[4];
        #pragma unroll
        for (int i = 0; i < 4; ++i) {
            const int ar = wm + i*16 + fm;
            ah[i] = *(const f16x8*)&lds[0*4096 + ar*32 + fko];
            al[i] = *(const f16x8*)&lds[1*4096 + ar*32 + fko];
        }
        #pragma unroll
        for (int j = 0; j < 4; ++j) {
            const int br = wn + j*16 + fm;
            f16x8 bh = *(const f16x8*)&lds[2*4096 + br*32 + fko];
            f16x8 bl = *(const f16x8*)&lds[3*4096 + br*32 + fko];
            #pragma unroll
            for (int i = 0; i < 4; ++i) {
                acc0[i][j] = __builtin_amdgcn_mfma_f32_16x16x32_f16(ah[i], bh, acc0[i][j], 0, 0, 0);
                acc1[i][j] = __builtin_amdgcn_mfma_f32_16x16x32_f16(ah[i], bl, acc1[i][j], 0, 0, 0);
                acc1[i][j] = __builtin_amdgcn_mfma_f32_16x16x32_f16(al[i], bh, acc1[i][j], 0, 0, 0);
            }
        }
    }
    // epilogue: C/D layout col=lane&15, row=(lane>>4)*4+reg (m89-verified)
    #pragma unroll
    for (int i = 0; i < 4; ++i)
        #pragma unroll
        for (int j = 0; j < 4; ++j) {
            const int col = bn + wn + j*16 + fm;
            const float bv = bias[col];
            #pragma unroll
            for (int r = 0; r < 4; ++r) {
                const int row = bm + wm + i*16 + (lane >> 4)*4 + r;
                float v = acc0[i][j][r] + acc1[i][j][r] * RINV + bv;
                if (OUTMODE == 0) {
                    Cf[(size_t)row * N + col] = v;
                } else {
                    v = gelu_f(v);
                    _Float16 h = hi16(v);
                    Oh[(size_t)row * N + col] = h;
                    Ol[(size_t)row * N + col] = lo16(v, h);
                }
            }
        }
}

// ============ weight transpose + fp16 split: out[n][k] = in[k][n] ============
__global__ __launch_bounds__(256) void k_tsplit(
    const float* __restrict__ in, _Float16* __restrict__ oh,
    _Float16* __restrict__ ol, int K, int N)
{
    __shared__ float tile[32][33];
    const int bx = blockIdx.x * 32;   // N offset
    const int by = blockIdx.y * 32;   // K offset
    const int t = threadIdx.x, r = t >> 5, c = t & 31;
    #pragma unroll
    for (int p = 0; p < 4; ++p)
        tile[r + p*8][c] = in[(size_t)(by + r + p*8) * N + bx + c];
    __syncthreads();
    #pragma unroll
    for (int p = 0; p < 4; ++p) {
        const int nl = r + p*8;
        float v = tile[c][nl];
        _Float16 h = hi16(v);
        oh[(size_t)(bx + nl) * K + by + c] = h;
        ol[(size_t)(bx + nl) * K + by + c] = lo16(v, h);
    }
}

// ============ elementwise fp16 split (x rows) ============
__global__ __launch_bounds__(256) void k_xsplit(
    const float* __restrict__ in, _Float16* __restrict__ oh,
    _Float16* __restrict__ ol)
{
    const size_t i = ((size_t)blockIdx.x * 256 + threadIdx.x) * 4;
    float4 v = *(const float4*)(in + i);
    _Float16 h0 = hi16(v.x), h1 = hi16(v.y), h2 = hi16(v.z), h3 = hi16(v.w);
    f16x4v h = {h0, h1, h2, h3};
    f16x4v l = {lo16(v.x,h0), lo16(v.y,h1), lo16(v.z,h2), lo16(v.w,h3)};
    *(f16x4v*)(oh + i) = h;
    *(f16x4v*)(ol + i) = l;
}

// ============ init layernorm ============
__global__ __launch_bounds__(256) void k_ln_init(
    const float* __restrict__ y, const float* __restrict__ g,
    const float* __restrict__ b, float* __restrict__ c0, int rowoff)
{
    const int row = rowoff + blockIdx.x;   // n*32 + s
    const float* yr = y + (size_t)blockIdx.x * DD;
    const int t = threadIdx.x;
    float v0 = yr[t], v1 = yr[t + 256];
    __shared__ float sb[8];
    float s1 = block_reduce_sum(v0 + v1, sb);
    float s2 = block_reduce_sum(v0*v0 + v1*v1, sb);
    float mu = s1 * (1.f/512.f);
    float rstd = rsqrtf(s2 * (1.f/512.f) - mu*mu + 1e-5f);
    float* o = c0 + (size_t)row * DD;      // c0: [256][1][32][512], stride 32
    o[t]       = (v0 - mu) * rstd * g[t]       + b[t];
    o[t + 256] = (v1 - mu) * rstd * g[t + 256] + b[t + 256];
}

__global__ void k_init_state(float* accu, float* bm) {
    int i = blockIdx.x * blockDim.x + threadIdx.x;
    if (i < NB) { accu[i] = 0.f; bm[i] = 1.f; }
}

// ============ pair scores (fp32, content addressing via ST) ============
// mode 0 (full, i=0): row r -> n=r/S, s=r%S; content row = (n*ST + s).
// mode 1 (incremental): row r -> nk=r>>1, slot=r&1, jw=pos[nk]-1+slot.
__global__ __launch_bounds__(256) void k_score(
    const float* __restrict__ content, const float* __restrict__ Wd1,
    const float* __restrict__ bd1, const float* __restrict__ Wd2,
    const float* __restrict__ bd2, float* __restrict__ w,
    const int* __restrict__ posb, int mode, int S, int nrows, int ST)
{
    __shared__ float cat[8][1024];
    const int t = threadIdx.x;
    const float* src[8];
    int wix[8]; bool valid[8];
    #pragma unroll
    for (int j = 0; j < 8; ++j) {
        int r = blockIdx.x * 8 + j;
        if (r >= nrows) r = nrows - 1;
        if (mode == 0) {
            int n = r / S, s = r - n * S;
            src[j]   = content + ((size_t)n * ST + s) * DD;
            wix[j]   = (n*BEAM + 0)*S0 + s;
            valid[j] = true;
        } else {
            int nk = r >> 1, slot = r & 1;
            int s = posb[nk];
            int jw = s - 1 + slot;
            valid[j] = (jw >= 0 && jw < S);
            int jc = jw < 0 ? 0 : (jw > S-1 ? S-1 : jw);
            src[j] = content + ((size_t)nk * ST + jc) * DD;
            wix[j] = nk * S0 + jc;
        }
    }
    #pragma unroll
    for (int j = 0; j < 8; ++j)
        *(float4*)&cat[j][4*t] = *(const float4*)(src[j] + 4*t);
    __syncthreads();

    const int c0 = 2*t, c1 = 2*t + 1;
    float a0[8] = {0,0,0,0,0,0,0,0}, a1[8] = {0,0,0,0,0,0,0,0};
    for (int k4 = 0; k4 < 1024; k4 += 4) {
        float2 w0 = *(const float2*)(Wd1 + (size_t)(k4+0)*DD + c0);
        float2 w1 = *(const float2*)(Wd1 + (size_t)(k4+1)*DD + c0);
        float2 w2 = *(const float2*)(Wd1 + (size_t)(k4+2)*DD + c0);
        float2 w3 = *(const float2*)(Wd1 + (size_t)(k4+3)*DD + c0);
        #pragma unroll
        for (int j = 0; j < 8; ++j) {
            float4 a = *(const float4*)&cat[j][k4];
            a0[j] = fmaf(a.x, w0.x, a0[j]); a1[j] = fmaf(a.x, w0.y, a1[j]);
            a0[j] = fmaf(a.y, w1.x, a0[j]); a1[j] = fmaf(a.y, w1.y, a1[j]);
            a0[j] = fmaf(a.z, w2.x, a0[j]); a1[j] = fmaf(a.z, w2.y, a1[j]);
            a0[j] = fmaf(a.w, w3.x, a0[j]); a1[j] = fmaf(a.w, w3.y, a1[j]);
        }
    }
    const float b0 = bd1[c0], b1 = bd1[c1];
    const float u0 = Wd2[c0], u1 = Wd2[c1];
    const float bd2v = bd2[0];
    __syncthreads();
    float* red = &cat[0][0];
    #pragma unroll
    for (int j = 0; j < 8; ++j) {
        float h0 = gelu_f(a0[j] + b0);
        float h1 = gelu_f(a1[j] + b1);
        red[j*256 + t] = h0*u0 + h1*u1;
    }
    __syncthreads();
    for (int off = 128; off > 0; off >>= 1) {
        if (t < off) {
            #pragma unroll
            for (int j = 0; j < 8; ++j) red[j*256 + t] += red[j*256 + t + off];
        }
        __syncthreads();
    }
    #pragma unroll
    for (int j = 0; j < 8; ++j)
        if (t == j && valid[j] && blockIdx.x*8 + j < nrows)
            w[wix[j]] = red[j*256] + bd2v;
}

// ============ top-k + beam selection + fused score-cache gather ============
__global__ __launch_bounds__(64) void k_topk(
    const float* __restrict__ w, const float* __restrict__ accu,
    const float* __restrict__ bmask, const float* __restrict__ maskg,
    int iiter, int B, int S, int topk, int do_bsel,
    int* __restrict__ parent, int* __restrict__ posb,
    float* __restrict__ accu_out, float* __restrict__ bm_out,
    float* __restrict__ wnew, int Snew, int dow)
{
    const int n = blockIdx.x, lane = threadIdx.x;
    __shared__ int   selpos_s[BEAM][BEAM];
    __shared__ float nscore_s[BEAM][BEAM];
    __shared__ int   par_s[BEAM], pos_s[BEAM];
    const float* mrow = maskg + n*S0 + (iiter + 1);
    const float mk   = (lane < S) ? mrow[lane] : 0.f;
    const float done = 1.f - mrow[0];
    for (int b = 0; b < B; ++b) {
        float ml;
        if (lane < S) {
            float wv = w[(n*BEAM + b)*S0 + lane];
            ml = (mk > 0.f) ? wv : -1e9f;
        } else ml = -INFINITY;
        float mx = ml;
        #pragma unroll
        for (int o = 32; o > 0; o >>= 1) mx = fmaxf(mx, __shfl_xor(mx, o));
        float e = (lane < S) ? expf(ml - mx) * mk : 0.f;
        float es = e;
        #pragma unroll
        for (int o = 32; o > 0; o >>= 1) es += __shfl_xor(es, o);
        const float den = es + 1e-20f;
        float mlc = ml;
        for (int ts = 0; ts < topk; ++ts) {
            unsigned int fb = __float_as_uint(mlc);
            unsigned int ok = (fb & 0x80000000u) ? ~fb : (fb | 0x80000000u);
            unsigned long long key =
                ((unsigned long long)ok << 32) | (unsigned int)(63 - lane);
            if (lane >= S) key = 0ull;
            unsigned long long km = key;
            #pragma unroll
            for (int o = 32; o > 0; o >>= 1) {
                unsigned long long oth = __shfl_xor(km, o);
                km = (oth > km) ? oth : km;
            }
            int sidx = 63 - (int)(km & 0xffffffffull);
            float esel = __shfl(e, sidx);
            if (lane == 0) {
                selpos_s[b][ts] = sidx;
                nscore_s[b][ts] = logf(esel / den + 1e-20f);
            }
            if (lane == sidx) mlc = -INFINITY;
        }
    }
    __syncthreads();
    if (lane == 0) {
        float acand[BEAM*BEAM], bcand[BEAM*BEAM];
        const int C = B * topk;
        for (int b = 0; b < B; ++b)
            for (int tt = 0; tt < topk; ++tt) {
                int c = b*topk + tt;
                acand[c] = accu[n*BEAM + b] + nscore_s[b][tt];
                float nb = done * ((tt == 0) ? 1.f : 0.f) + (1.f - done);
                bcand[c] = bmask[n*BEAM + b] * nb;
            }
        bool used[BEAM*BEAM];
        for (int c = 0; c < C; ++c) used[c] = false;
        for (int k = 0; k < BEAM; ++k) {
            int bestc;
            if (do_bsel) {
                bestc = 0; float bv = -INFINITY;
                for (int c = 0; c < C; ++c) {
                    if (used[c]) continue;
                    float v = (bcand[c] > 0.f) ? acand[c] : -1e9f;
                    if (v > bv) { bv = v; bestc = c; }
                }
                used[bestc] = true;
            } else bestc = k;
            parent[n*BEAM + k]   = bestc / topk;
            posb[n*BEAM + k]     = selpos_s[bestc / topk][bestc % topk];
            par_s[k] = bestc / topk;
            pos_s[k] = selpos_s[bestc / topk][bestc % topk];
            accu_out[n*BEAM + k] = acand[bestc];
            bm_out[n*BEAM + k]   = bcand[bestc];
        }
    }
    __syncthreads();
    if (dow) {   // fused score-cache gather
        for (int k = 0; k < BEAM; ++k) {
            const int p = par_s[k], s = pos_s[k];
            if (lane < Snew) {
                float v = 0.f;
                if (lane < s - 1)      v = w[(n*BEAM + p)*S0 + lane];
                else if (lane > s)     v = w[(n*BEAM + p)*S0 + lane + 1];
                wnew[(n*BEAM + k)*S0 + lane] = v;
            }
        }
    }
}

// ============ gather [l,r] rows -> fp16 split A for GEMM1 ============
__global__ __launch_bounds__(256) void k_lrgather(
    const float* __restrict__ content, const int* __restrict__ parent,
    const int* __restrict__ posb, int finalflag, int BA, int ST,
    _Float16* __restrict__ A1h, _Float16* __restrict__ A1l)
{
    const int row = blockIdx.x;            // n*BEAM + k
    const int n = row / BEAM, k = row % BEAM;
    const int p = finalflag ? k : parent[row];
    const int s = finalflag ? 0 : posb[row];
    const float* src = content + ((size_t)(n*BA + p)*ST + s) * DD;  // 1024 contiguous
    const int t = threadIdx.x;
    float4 v = *(const float4*)(src + 4*t);
    _Float16 h0 = hi16(v.x), h1 = hi16(v.y), h2 = hi16(v.z), h3 = hi16(v.w);
    f16x4v h = {h0, h1, h2, h3};
    f16x4v l = {lo16(v.x,h0), lo16(v.y,h1), lo16(v.z,h2), lo16(v.w,h3)};
    *(f16x4v*)(A1h + (size_t)row*1024 + 4*t) = h;
    *(f16x4v*)(A1l + (size_t)row*1024 + 4*t) = l;
}

// ============ gate softmax + mix + layernorm ============
__global__ __launch_bounds__(256) void k_combine(
    const float* __restrict__ cc, const float* __restrict__ content,
    const int* __restrict__ parent, const int* __restrict__ posb,
    int finalflag, int BA, int ST,
    const float* __restrict__ gp, const float* __restrict__ bp,
    float* __restrict__ nv)
{
    const int row = blockIdx.x, t = threadIdx.x;
    const int n = row / BEAM, k = row % BEAM;
    const int p = finalflag ? k : parent[row];
    const int s = finalflag ? 0 : posb[row];
    const float* c = cc + (size_t)row * CHID;
    const float* l = content + ((size_t)(n*BA + p)*ST + s) * DD;
    const float* r = l + DD;
    float o[2];
    #pragma unroll
    for (int e = 0; e < 2; ++e) {
        int d = t + 256*e;
        float c0 = c[d], c1 = c[DD + d], c2 = c[2*DD + d], c3 = c[3*DD + d];
        float m = fmaxf(c0, fmaxf(c1, c2));
        float e0 = expf(c0 - m), e1 = expf(c1 - m), e2 = expf(c2 - m);
        float inv = 1.f / (e0 + e1 + e2);
        o[e] = (e0*l[d] + e1*r[d] + e2*c3) * inv;
    }
    __shared__ float sb[8];
    float s1 = block_reduce_sum(o[0] + o[1], sb);
    float s2 = block_reduce_sum(o[0]*o[0] + o[1]*o[1], sb);
    float mu = s1 * (1.f/512.f);
    float rstd = rsqrtf(s2 * (1.f/512.f) - mu*mu + 1e-5f);
    #pragma unroll
    for (int e = 0; e < 2; ++e) {
        int d = t + 256*e;
        nv[(size_t)row*DD + d] = (o[e] - mu) * rstd * gp[d] + bp[d];
    }
}

// ============ content rebuild (read stride STo/BAo, write stride 31) ============
__global__ __launch_bounds__(256) void k_rebuild(
    const float* __restrict__ oldc, const float* __restrict__ nv,
    const int* __restrict__ parent, const int* __restrict__ posb,
    const float* __restrict__ maskg, int iiter, int Spnew, int BAo, int STo,
    float* __restrict__ newc)
{
    const int nk = blockIdx.x;
    const int n = nk / BEAM;
    const int p = parent[nk], s = posb[nk];
    const float done = maskg[n*S0 + iiter + 1];
    const float4* ob = (const float4*)(oldc + ((size_t)(n*BAo + p) * STo) * DD);
    const float4* nb = (const float4*)(nv + (size_t)nk * DD);
    float4* dst = (float4*)(newc + ((size_t)nk * 31) * DD);
    const int total = Spnew * 128;
    for (int idx = threadIdx.x; idx < total; idx += 256) {
        int j = idx >> 7, d = idx & 127;
        float4 v = (j < s) ? ob[j*128 + d] : (j == s ? nb[d] : ob[(j+1)*128 + d]);
        if (done != 1.0f) {
            float4 tr = ob[j*128 + d];
            v.x = done*v.x + (1.f-done)*tr.x;  v.y = done*v.y + (1.f-done)*tr.y;
            v.z = done*v.z + (1.f-done)*tr.z;  v.w = done*v.w + (1.f-done)*tr.w;
        }
        dst[j*128 + d] = v;
    }
}

// ============ final beam softmax mix ============
__global__ __launch_bounds__(256) void k_final(
    const float* __restrict__ nv, const float* __restrict__ accu,
    const float* __restrict__ bmv, float* __restrict__ out)
{
    const int n = blockIdx.x, t = threadIdx.x;
    float sc[BEAM];
    #pragma unroll
    for (int k = 0; k < BEAM; ++k) {
        float m = bmv[n*BEAM + k];
        sc[k] = m * accu[n*BEAM + k] + (1.f - m) * (-999999.f);
    }
    float mx = sc[0];
    #pragma unroll
    for (int k = 1; k < BEAM; ++k) mx = fmaxf(mx, sc[k]);
    float e[BEAM], den = 0.f;
    #pragma unroll
    for (int k = 0; k < BEAM; ++k) { e[k] = expf(sc[k] - mx); den += e[k]; }
    const float inv = 1.f / den;
    #pragma unroll
    for (int i2 = 0; i2 < 2; ++i2) {
        int d = t + 256*i2;
        float s = 0.f;
        #pragma unroll
        for (int k = 0; k < BEAM; ++k)
            s += e[k]*inv * nv[((size_t)n*BEAM + k)*DD + d];
        out[(size_t)n*DD + d] = s;
    }
}

extern "C" void kernel_launch(void* const* d_in, const int* in_sizes, int n_in,
                              void* d_out, int out_size, void* d_ws, size_t ws_size,
                              hipStream_t stream) {
    (void)in_sizes; (void)n_in; (void)out_size; (void)ws_size;
    const float* x    = (const float*)d_in[0];
    const float* mask = (const float*)d_in[1];
    const float* Wi   = (const float*)d_in[2];
    const float* bi   = (const float*)d_in[3];
    const float* g1   = (const float*)d_in[4];
    const float* b1   = (const float*)d_in[5];
    const float* Wd1  = (const float*)d_in[6];
    const float* bd1  = (const float*)d_in[7];
    const float* Wd2  = (const float*)d_in[8];
    const float* bd2  = (const float*)d_in[9];
    const float* Wc1  = (const float*)d_in[10];
    const float* bc1  = (const float*)d_in[11];
    const float* Wc2  = (const float*)d_in[12];
    const float* bc2  = (const float*)d_in[13];
    const float* g2   = (const float*)d_in[14];
    const float* b2   = (const float*)d_in[15];
    float* out = (float*)d_out;

    // ---- workspace carve-up (bytes), ~214 MB ----
    char* p = (char*)d_ws;
    float* cbigA = (float*)p;            p += (size_t)NN*BEAM*31*DD*4;   // 81,264,640
    float* cbigB = (float*)p;            p += (size_t)NN*BEAM*31*DD*4;   // 81,264,640
    float* c0    = cbigB;                // [256][32][512] alias: cbigB untouched until rebuild(i=1)
    _Float16* Wc1th = (_Float16*)p;      p += (size_t)CHID*1024*2;        // 4,194,304
    _Float16* Wc1tl = (_Float16*)p;      p += (size_t)CHID*1024*2;
    _Float16* Wc2th = (_Float16*)p;      p += (size_t)CHID*CHID*2;        // 8,388,608
    _Float16* Wc2tl = (_Float16*)p;      p += (size_t)CHID*CHID*2;
    float* wA   = (float*)p;             p += (size_t)NB*S0*4;            // 163,840
    float* wB   = (float*)p;             p += (size_t)NB*S0*4;
    float* accA = (float*)p;             p += NB*4;
    float* accB = (float*)p;             p += NB*4;
    float* bmA  = (float*)p;             p += NB*4;
    float* bmB  = (float*)p;             p += NB*4;
    int* parent = (int*)p;               p += NB*4;
    int* posb   = (int*)p;               p += NB*4;
    char* S1 = p;                        p += (size_t)NB*CHID*2*2;        // 10,485,760
    char* S2 = p;                        p += (size_t)NB*CHID*4;          // 10,485,760
    char* S3 = p;                        p += (size_t)NB*1024*4;          // 5,242,880
    // region roles:
    _Float16* Hh  = (_Float16*)S1;                    // gemm1 out hi [1280][2048]
    _Float16* Hl  = (_Float16*)(S1 + (size_t)NB*CHID*2);
    _Float16* A1h = (_Float16*)S2;                    // gemm1 A hi [1280][1024]
    _Float16* A1l = (_Float16*)(S2 + (size_t)NB*1024*2);
    float* cb  = (float*)S2;             // gemm2 out (overwrites A1 — A1 dead by then)
    float* nvb = (float*)S3;
    // init-only aliases:
    _Float16* xh    = (_Float16*)S1;                  // x chunk hi [4096][512]
    _Float16* xl    = (_Float16*)(S1 + (size_t)4096*512*2);
    float* ybufc    = (float*)S2;                     // init gemm out chunk
    _Float16* Wih   = (_Float16*)(S3 + (size_t)NB*DD*4);
    _Float16* Wil   = (_Float16*)(S3 + (size_t)NB*DD*4 + (size_t)WDIM*DD*2);

    // ---- weight prep ----
    k_tsplit<<<dim3(CHID/32, 1024/32), 256, 0, stream>>>(Wc1, Wc1th, Wc1tl, 1024, CHID);
    k_tsplit<<<dim3(CHID/32, CHID/32), 256, 0, stream>>>(Wc2, Wc2th, Wc2tl, CHID, CHID);
    k_tsplit<<<dim3(DD/32, WDIM/32), 256, 0, stream>>>(Wi, Wih, Wil, WDIM, DD);
    k_init_state<<<(NB + 255)/256, 256, 0, stream>>>(accA, bmA);

    // ---- init: content0 = LN(x@Wi+bi), 2 chunks of 4096 rows ----
    for (int c = 0; c < 2; ++c) {
        const float* xc = x + (size_t)c*4096*WDIM;
        k_xsplit<<<(4096*WDIM)/1024, 256, 0, stream>>>(xc, xh, xl);
        k_mfma_gemm<0><<<dim3(DD/128, 4096/128), 256, 0, stream>>>(
            xh, xl, Wih, Wil, bi, ybufc, nullptr, nullptr, 4096, DD, WDIM);
        k_ln_init<<<4096, 256, 0, stream>>>(ybufc, g1, b1, c0, c*4096);
    }
    // full scores at i=0 (B=1, S=31); content stride 32
    k_score<<<(NN*31)/8, 256, 0, stream>>>(c0, Wd1, bd1, Wd2, bd2, wA, nullptr, 0, 31, NN*31, 32);

    float *ccur = c0, *cnxt = cbigA;
    int BAo = 1, STo = 32;
    float *wcur = wA, *wnxt = wB;
    float *acur = accA, *anxt = accB, *bcur = bmA, *bnxt = bmB;
    for (int i = 0; i < 30; ++i) {
        const int B  = (i == 0) ? 1 : BEAM;
        const int S  = 31 - i;            // pair count at this iteration
        const int tk = (S < BEAM) ? S : BEAM;
        const int dob = (B*tk > BEAM) ? 1 : 0;
        k_topk<<<NN, 64, 0, stream>>>(wcur, acur, bcur, mask, i, B, S, tk, dob,
                                      parent, posb, anxt, bnxt, wnxt, S - 1, (i < 29) ? 1 : 0);
        k_lrgather<<<NB, 256, 0, stream>>>(ccur, parent, posb, 0, BAo, STo, A1h, A1l);
        k_mfma_gemm<1><<<dim3(CHID/128, NB/128), 256, 0, stream>>>(
            A1h, A1l, Wc1th, Wc1tl, bc1, nullptr, Hh, Hl, NB, CHID, 2*DD);
        k_mfma_gemm<0><<<dim3(CHID/128, NB/128), 256, 0, stream>>>(
            Hh, Hl, Wc2th, Wc2tl, bc2, cb, nullptr, nullptr, NB, CHID, CHID);
        k_combine<<<NB, 256, 0, stream>>>(cb, ccur, parent, posb, 0, BAo, STo, g2, b2, nvb);
        k_rebuild<<<NB, 256, 0, stream>>>(ccur, nvb, parent, posb, mask, i, 31 - i, BAo, STo, cnxt);
        if (i < 29)
            k_score<<<(NB*2)/8, 256, 0, stream>>>(cnxt, Wd1, bd1, Wd2, bd2, wnxt,
                                                  posb, 1, S - 1, NB*2, 31);
        // swap
        float* tp;
        if (i == 0) { ccur = cbigA; cnxt = cbigB; }
        else { tp = ccur; ccur = cnxt; cnxt = tp; }
        BAo = BEAM; STo = 31;
        tp = wcur; wcur = wnxt; wnxt = tp;
        tp = acur; acur = anxt; anxt = tp;
        tp = bcur; bcur = bnxt; bnxt = tp;
    }
    // final compose: l = content[:,:,0], r = content[:,:,1]
    k_lrgather<<<NB, 256, 0, stream>>>(ccur, parent, posb, 1, BEAM, 31, A1h, A1l);
    k_mfma_gemm<1><<<dim3(CHID/128, NB/128), 256, 0, stream>>>(
        A1h, A1l, Wc1th, Wc1tl, bc1, nullptr, Hh, Hl, NB, CHID, 2*DD);
    k_mfma_gemm<0><<<dim3(CHID/128, NB/128), 256, 0, stream>>>(
        Hh, Hl, Wc2th, Wc2tl, bc2, cb, nullptr, nullptr, NB, CHID, CHID);
    k_combine<<<NB, 256, 0, stream>>>(cb, ccur, parent, posb, 1, BEAM, 31, g2, b2, nvb);
    k_final<<<NN, 256, 0, stream>>>(nvb, acur, bcur, out);
}